// Round 1
// baseline (5512.557 us; speedup 1.0000x reference)
//
#include <hip/hip_runtime.h>

typedef __attribute__((ext_vector_type(8))) short short8;
typedef __attribute__((ext_vector_type(4))) float f32x4;

#define NN 4096     // neurons
#define NB 32       // batch
#define TSTEPS 291  // t = 0..290 (last record at t=290; steps 291..299 unused)
#define FF_T 300    // ff_input time stride
#define NBLK 256    // grid size == CU count; 1 block/CU capacity guaranteed

// float -> bf16 round-to-nearest-even, raw bits in a short
__device__ __forceinline__ short f2bf(float x) {
    unsigned u = __builtin_bit_cast(unsigned, x);
    unsigned r = (u + 0x7FFFu + ((u >> 16) & 1u)) >> 16;
    return (short)r;
}
__device__ __forceinline__ unsigned pack2bf(float x0, float x1) {
    return ((unsigned)(unsigned short)f2bf(x0))
         | (((unsigned)(unsigned short)f2bf(x1)) << 16);
}

// Coherent-point store/load (global_store/load_dword sc1 — bypass L2,
// visible cross-XCD without any wbl2 fence).
__device__ __forceinline__ void st_coh(int* p, int v) {
    __hip_atomic_store(p, v, __ATOMIC_RELAXED, __HIP_MEMORY_SCOPE_AGENT);
}
__device__ __forceinline__ int ld_coh(const int* p) {
    return __hip_atomic_load(p, __ATOMIC_RELAXED, __HIP_MEMORY_SCOPE_AGENT);
}

// rates fragment layout (units: shorts): [k>>5][m>>4][(k>>3)&3][m&15][k&7]
// This is exactly the 16x16x32 MFMA A-fragment lane order, so a consumer
// wave reads its whole K-slab as a contiguous stream: lane address =
// slab_base + kt*2048B + lane*16B (a0), +1024B (a1). Producer still emits
// exactly ONE packed dword per thread (its two neurons are adjacent k&7
// slots -> same dword).
__device__ __forceinline__ int foff(int m, int k) {
    return ((k >> 5) << 10) | ((m >> 4) << 9) | (((k >> 3) & 3) << 7)
         | ((m & 15) << 3) | (k & 7);
}

// Single-hop grid barrier: monotonic arrival counter at the coherence
// point. Arrival = one no-return agent atomicAdd (issued after
// __syncthreads has drained this block's sc1 rates stores, so counter
// visibility implies data visibility). Completion = ctr >= 256*epoch,
// polled by ONE lane per block with s_sleep throttle (256 pollers on one
// word — same poll traffic as the old `go` word, but the master-
// aggregation hop and the go-publication round trip are gone: the chain
// is now last-arrival-visible -> one poll period). Counter is never
// reset (292 epochs * 256 = 74752 << 2^31). Exactly one acquire fence
// (buffer_inv) per block per step keeps normal cached A-loads correct
// while preserving per-XCD L2 broadcast amplification.
__device__ __forceinline__ void grid_sync(int* __restrict__ ctr, int target) {
    __syncthreads();   // all waves: s_waitcnt vmcnt(0) — rates stores at L3
    if (threadIdx.x == 0) {
        __hip_atomic_fetch_add(ctr, 1, __ATOMIC_RELAXED, __HIP_MEMORY_SCOPE_AGENT);
        while (ld_coh(ctr) < target)
            __builtin_amdgcn_s_sleep(4);
    }
    __syncthreads();
    __builtin_amdgcn_fence(__ATOMIC_ACQUIRE, "agent");  // buffer_inv only
}

// Persistent kernel. One WG per CU; WG c owns output columns [16c,16c+16)
// for all 32 batches. W lives in registers as MFMA B-frags (128 VGPRs/wave)
// for the whole run. Per-neuron fp32 state (rec, rate, window-acc) in
// registers: thread owns elements (b = tid>>3, n = n0 + (tid&7)*2 + {0,1}).
__global__ __launch_bounds__(256, 1)
void rnn_kernel(const float* __restrict__ W,
                const float* __restrict__ ff,
                const float* __restrict__ rec0p,
                float* __restrict__ out,
                int* __restrict__ ctr,
                short* __restrict__ ratesA,
                short* __restrict__ ratesB)
{
    const int tid  = threadIdx.x;
    const int wave = tid >> 6;
    const int lane = tid & 63;
    const int n0   = blockIdx.x * 16;

    __shared__ float part[4][32][18];   // per-wave K-partials (padded)

    // per-thread state element indices
    const int sb  = tid >> 3;           // batch 0..31
    const int nl0 = (tid & 7) * 2;      // even neuron-local index 0..14
    const int fo  = foff(sb, n0 + nl0); // fragment dword slot (fo is even)

    // ---- init: rec0, rates0 = relu(ff[:,0] + rec0)
    const size_t sidx = (size_t)sb * NN + n0 + nl0;
    float rc0 = rec0p[sidx], rc1 = rec0p[sidx + 1];
    const float* ffbase = ff + ((size_t)sb * FF_T) * NN + n0 + nl0;
    float ffv0 = ffbase[0];
    float ffv1 = ffbase[1];
    float rt0 = fmaxf(ffv0 + rc0, 0.0f);
    float rt1 = fmaxf(ffv1 + rc1, 0.0f);
    float ac0 = 0.0f, ac1 = 0.0f;
    st_coh((int*)(ratesA + fo), (int)pack2bf(rt0, rt1));

    // ---- W (fp32 [k][n]) -> register bf16 B-fragments.
    // wave w covers k in [w*1024, (w+1)*1024); for K-step kt, lane holds
    // B[k = w*1024 + kt*32 + (lane>>4)*8 + j][n = n0 + (lane&15)], j=0..7
    short8 Bfr[32];
    {
        const int ncol  = n0 + (lane & 15);
        const size_t kb = (size_t)(wave * 1024 + ((lane >> 4) * 8));
        #pragma unroll
        for (int kt = 0; kt < 32; ++kt) {
            short8 f;
            #pragma unroll
            for (int j = 0; j < 8; ++j) {
                f[j] = f2bf(W[(kb + (size_t)kt * 32 + j) * NN + ncol]);
            }
            Bfr[kt] = f;
        }
    }

    grid_sync(ctr, NBLK);   // epoch 1: rates0 globally visible

    // A-loads: contiguous fragment stream. Wave w owns shorts
    // [w*32768, (w+1)*32768) of the buffer; per kt it reads two 1KB
    // fully-coalesced blocks (m-tile 0 and 1). Normal cached loads:
    // served from per-XCD L2 after one fill.
    const int wl = (wave << 15) + (lane << 3);

    for (int t = 0; t < TSTEPS; ++t) {
        const short* __restrict__ rbuf = (t & 1) ? ratesB : ratesA;
        short* __restrict__ wbuf       = (t & 1) ? ratesA : ratesB;

        f32x4 acc0 = {0.f, 0.f, 0.f, 0.f};
        f32x4 acc1 = {0.f, 0.f, 0.f, 0.f};
        const short* pw = rbuf + wl;
        #pragma unroll
        for (int kt = 0; kt < 32; ++kt) {
            short8 a0 = *(const short8*)(pw + (kt << 10));
            short8 a1 = *(const short8*)(pw + (kt << 10) + 512);
            acc0 = __builtin_amdgcn_mfma_f32_16x16x32_bf16(a0, Bfr[kt], acc0, 0, 0, 0);
            acc1 = __builtin_amdgcn_mfma_f32_16x16x32_bf16(a1, Bfr[kt], acc1, 0, 0, 0);
        }

        // C/D layout: col = lane&15, row = (lane>>4)*4 + reg  [m89-verified]
        const int prow = (lane >> 4) * 4;
        const int pcol = lane & 15;
        #pragma unroll
        for (int r = 0; r < 4; ++r) {
            part[wave][prow + r][pcol]      = acc0[r];
            part[wave][16 + prow + r][pcol] = acc1[r];
        }
        __syncthreads();

        // fused update on this thread's two elements (state in registers)
        const float h0 = part[0][sb][nl0] + part[1][sb][nl0]
                       + part[2][sb][nl0] + part[3][sb][nl0];
        const float h1 = part[0][sb][nl0+1] + part[1][sb][nl0+1]
                       + part[2][sb][nl0+1] + part[3][sb][nl0+1];
        rc0 = rc0 * 0.95122945f + h0 * 0.05f;   // exp(-dt/tau_syn), dt/tau_syn
        rc1 = rc1 * 0.95122945f + h1 * 0.05f;
        rt0 = rt0 * 0.90483743f + fmaxf(ffv0 + rc0, 0.0f) * 0.1f; // exp(-dt/tau), dt/tau
        rt1 = rt1 * 0.90483743f + fmaxf(ffv1 + rc1, 0.0f) * 0.1f;
        if (t >= 90) { ac0 += rt0; ac1 += rt1; }
        // publish new rates straight to the coherence point (sc1 store,
        // fragment layout — still exactly one dword per thread)
        st_coh((int*)(wbuf + fo), (int)pack2bf(rt0, rt1));

        // record: windows end at t = 100,110,...,290 (first window = 11 terms
        // /10, matching cs[100]-cs[89] in the reference)
        if (t >= 100 && (t % 10) == 0) {
            const int w = (t - 100) / 10;
            float* op = out + ((size_t)sb * 20 + w) * NN + n0 + nl0;
            op[0] = ac0 * 0.1f;
            op[1] = ac1 * 0.1f;
            ac0 = 0.0f; ac1 = 0.0f;
        }

        // prefetch next step's ff BEFORE the barrier so its HBM latency
        // hides under the wait; sync is skipped after the final step.
        if (t + 1 < TSTEPS) {
            const float* ffp = ffbase + (size_t)(t + 1) * NN;
            const float nf0 = ffp[0];
            const float nf1 = ffp[1];
            grid_sync(ctr, NBLK * (t + 2));
            ffv0 = nf0;
            ffv1 = nf1;
        }
    }
}

extern "C" void kernel_launch(void* const* d_in, const int* in_sizes, int n_in,
                              void* d_out, int out_size, void* d_ws, size_t ws_size,
                              hipStream_t stream)
{
    const float* W    = (const float*)d_in[0];   // Wab_T [4096,4096] fp32, row-major [k][n]
    const float* ff   = (const float*)d_in[1];   // [32,300,4096] fp32
    const float* rec0 = (const float*)d_in[2];   // [32,4096] fp32
    float* out = (float*)d_out;                  // [32,20,4096] fp32

    int*   ctr    = (int*)d_ws;                   // monotonic arrival counter
    short* ratesA = (short*)((char*)d_ws + 4096); // bf16 rates double buffer
    short* ratesB = ratesA + NB * NN;

    hipMemsetAsync(d_ws, 0, 4096, stream);        // graph-capturable memset node

    rnn_kernel<<<dim3(NBLK), dim3(256), 0, stream>>>(W, ff, rec0, out,
                                                     ctr, ratesA, ratesB);
}